// Round 2
// baseline (2086.281 us; speedup 1.0000x reference)
//
#include <hip/hip_runtime.h>
#include <hip/hip_bf16.h>

#define B_   32
#define T_   2048
#define DIN  1024
#define DHID 2048

typedef __attribute__((ext_vector_type(8))) short bf16x8;   // 8 bf16 = 4 VGPRs
typedef __attribute__((ext_vector_type(4))) float f32x4;
typedef __attribute__((ext_vector_type(4))) int   i32x4;

union BF8 { bf16x8 v; i32x4 i; unsigned int u[4]; };

// fp32 -> bf16 round-to-nearest-even, pure integer ops
__device__ inline unsigned int f2bf_u(float f) {
    unsigned int u = __float_as_uint(f);
    return (u + 0x7FFFu + ((u >> 16) & 1u)) >> 16;
}
__device__ inline unsigned int pack2bf(float a, float b) {
    return f2bf_u(a) | (f2bf_u(b) << 16);
}

// ---- kernel 0: W1 fp32 [DHID][DIN] -> bf16 (ushort) same layout ----
__global__ void convert_w1(const float* __restrict__ W1,
                           unsigned short* __restrict__ W1b) {
    int idx = blockIdx.x * blockDim.x + threadIdx.x;   // one float4 per thread
    const float4* in = (const float4*)W1;
    float4 f = in[idx];
    unsigned int lo = pack2bf(f.x, f.y);
    unsigned int hi = pack2bf(f.z, f.w);
    ((uint2*)W1b)[idx] = uint2{lo, hi};
}

// ---- kernel 1: fused GEMM + bias + relu + masked column-sum ----
// block: 256 threads = 4 waves (2x2), block tile 64(m) x 128(n), n-loop inside
// wave tile: 32(m) x 64(n) -> acc[2][4] of 16x16 MFMA tiles
__global__ void scorer_gemm(const float* __restrict__ hin,
                            const int*   __restrict__ text_len,
                            const unsigned short* __restrict__ W1b,
                            const float* __restrict__ b1,
                            float*       __restrict__ pooled) {
    const int tt  = blockIdx.x;          // t-tile (64 rows)
    const int b   = blockIdx.y;
    const int len = text_len[b];
    const int t0  = tt * 64;
    if (t0 >= len) return;               // fully masked block: skip

    const int tid  = threadIdx.x;
    const int lane = tid & 63;
    const int wid  = tid >> 6;           // 0..3
    const int wrow = wid >> 1;           // m offset 32*wrow
    const int wcol = wid & 1;            // n offset 64*wcol
    const int quad = lane >> 4;          // 0..3
    const int l15  = lane & 15;

    // A fragment base pointers: row = t0 + wrow*32 + mi*16 + l15, k off = quad*8
    const float* aptr[2];
#pragma unroll
    for (int mi = 0; mi < 2; ++mi) {
        int t = t0 + wrow * 32 + mi * 16 + l15;
        aptr[mi] = hin + ((size_t)b * T_ + t) * DIN + quad * 8;
    }

    for (int nout = 0; nout < DHID / 128; ++nout) {
        const int nbase = nout * 128;
        f32x4 acc[2][4] = {};
        const unsigned short* bptr[4];
        float b1v[4];
#pragma unroll
        for (int ni = 0; ni < 4; ++ni) {
            int n = nbase + wcol * 64 + ni * 16 + l15;
            bptr[ni] = W1b + (size_t)n * DIN + quad * 8;
            b1v[ni]  = b1[n];
        }

        for (int k = 0; k < DIN; k += 32) {
            BF8 a[2], w[4];
#pragma unroll
            for (int mi = 0; mi < 2; ++mi) {
                float4 f0 = *(const float4*)(aptr[mi] + k);
                float4 f1 = *(const float4*)(aptr[mi] + k + 4);
                a[mi].u[0] = pack2bf(f0.x, f0.y);
                a[mi].u[1] = pack2bf(f0.z, f0.w);
                a[mi].u[2] = pack2bf(f1.x, f1.y);
                a[mi].u[3] = pack2bf(f1.z, f1.w);
            }
#pragma unroll
            for (int ni = 0; ni < 4; ++ni)
                w[ni].i = *(const i32x4*)(bptr[ni] + k);
#pragma unroll
            for (int mi = 0; mi < 2; ++mi)
#pragma unroll
                for (int ni = 0; ni < 4; ++ni)
                    acc[mi][ni] = __builtin_amdgcn_mfma_f32_16x16x32_bf16(
                        a[mi].v, w[ni].v, acc[mi][ni], 0, 0, 0);
        }

        // epilogue: +b1, relu, mask t<len, reduce over m, atomicAdd to pooled
        // C/D layout: col = lane&15 (n), row = quad*4 + reg (m)
#pragma unroll
        for (int ni = 0; ni < 4; ++ni) {
            float colsum = 0.f;
#pragma unroll
            for (int mi = 0; mi < 2; ++mi) {
                int trow = t0 + wrow * 32 + mi * 16 + quad * 4;
#pragma unroll
                for (int r = 0; r < 4; ++r) {
                    float v = acc[mi][ni][r] + b1v[ni];
                    v = v > 0.f ? v : 0.f;
                    if (trow + r < len) colsum += v;
                }
            }
            colsum += __shfl_xor(colsum, 16);
            colsum += __shfl_xor(colsum, 32);
            if (quad == 0) {
                int n = nbase + wcol * 64 + ni * 16 + l15;
                atomicAdd(&pooled[b * DHID + n], colsum);
            }
        }
    }
}

// ---- kernel 2: score[b][tag] = pooled[b]·W2[tag] / len + b2[tag] ----
__global__ void finalize_k(const float* __restrict__ pooled,
                           const int*   __restrict__ text_len,
                           const float* __restrict__ W2,
                           const float* __restrict__ b2,
                           float*       __restrict__ out) {
    int b = blockIdx.x;
    int tid = threadIdx.x;
    float s0 = 0.f, s1 = 0.f;
    for (int hh = tid; hh < DHID; hh += 256) {
        float p = pooled[b * DHID + hh];
        s0 += p * W2[hh];
        s1 += p * W2[DHID + hh];
    }
#pragma unroll
    for (int off = 32; off > 0; off >>= 1) {
        s0 += __shfl_down(s0, off);
        s1 += __shfl_down(s1, off);
    }
    __shared__ float r0[4], r1[4];
    int wid = tid >> 6, lane = tid & 63;
    if (lane == 0) { r0[wid] = s0; r1[wid] = s1; }
    __syncthreads();
    if (tid == 0) {
        float inv = 1.0f / (float)text_len[b];
        out[b * 2 + 0] = (r0[0] + r0[1] + r0[2] + r0[3]) * inv + b2[0];
        out[b * 2 + 1] = (r1[0] + r1[1] + r1[2] + r1[3]) * inv + b2[1];
    }
}

extern "C" void kernel_launch(void* const* d_in, const int* in_sizes, int n_in,
                              void* d_out, int out_size, void* d_ws, size_t ws_size,
                              hipStream_t stream) {
    const float* hin      = (const float*)d_in[0];
    const int*   text_len = (const int*)  d_in[1];
    const float* W1       = (const float*)d_in[2];
    const float* b1       = (const float*)d_in[3];
    const float* W2       = (const float*)d_in[4];
    const float* b2       = (const float*)d_in[5];
    float* out = (float*)d_out;

    unsigned short* W1b = (unsigned short*)d_ws;                      // 4 MB
    float* pooled = (float*)((char*)d_ws + (size_t)DHID * DIN * 2);   // 256 KB

    (void)hipMemsetAsync(pooled, 0, B_ * DHID * sizeof(float), stream);
    convert_w1<<<(DHID * DIN / 4) / 256, 256, 0, stream>>>(W1, W1b);

    dim3 grid(T_ / 64, B_);
    scorer_gemm<<<grid, 256, 0, stream>>>(hin, text_len, W1b, b1, pooled);

    finalize_k<<<B_, 256, 0, stream>>>(pooled, text_len, W2, b2, out);
}

// Round 3
// 770.714 us; speedup vs baseline: 2.7069x; 2.7069x over previous
//
#include <hip/hip_runtime.h>
#include <hip/hip_bf16.h>

#define B_   32
#define T_   2048
#define DIN  1024
#define DHID 2048
#define BM   128
#define BN   128
#define BK   64

typedef __attribute__((ext_vector_type(8))) short bf16x8;   // 8 bf16 = 4 VGPRs
typedef __attribute__((ext_vector_type(4))) float f32x4;
typedef __attribute__((ext_vector_type(4))) int   i32x4;

union BF8 { bf16x8 v; i32x4 i; unsigned int u[4]; };

// fp32 -> bf16 round-to-nearest-even, pure integer ops
__device__ inline unsigned int f2bf_u(float f) {
    unsigned int u = __float_as_uint(f);
    return (u + 0x7FFFu + ((u >> 16) & 1u)) >> 16;
}
__device__ inline unsigned int pack2bf(float a, float b) {
    return f2bf_u(a) | (f2bf_u(b) << 16);
}

// ---- W1 fp32 [DHID][DIN] -> bf16 same layout ----
__global__ void convert_w1(const float* __restrict__ W1,
                           unsigned short* __restrict__ W1b) {
    int idx = blockIdx.x * blockDim.x + threadIdx.x;   // one float4 per thread
    float4 f = ((const float4*)W1)[idx];
    ((uint2*)W1b)[idx] = uint2{pack2bf(f.x, f.y), pack2bf(f.z, f.w)};
}

// ---- h fp32 [B,T,DIN] -> bf16; masked rows (t >= len) -> zeros ----
__global__ void convert_h(const float* __restrict__ h,
                          const int*   __restrict__ text_len,
                          unsigned short* __restrict__ hb) {
    size_t idx = (size_t)blockIdx.x * blockDim.x + threadIdx.x;  // 8 floats each
    size_t e0 = idx * 8;
    int b = (int)(e0 / ((size_t)T_ * DIN));
    int t = (int)((e0 / DIN) % T_);
    uint4 o;
    if (t < text_len[b]) {
        float4 f0 = ((const float4*)h)[idx * 2];
        float4 f1 = ((const float4*)h)[idx * 2 + 1];
        o.x = pack2bf(f0.x, f0.y);
        o.y = pack2bf(f0.z, f0.w);
        o.z = pack2bf(f1.x, f1.y);
        o.w = pack2bf(f1.z, f1.w);
    } else {
        o = uint4{0u, 0u, 0u, 0u};
    }
    ((uint4*)hb)[idx] = o;
}

// ---- main GEMM: LDS-staged 128x128x64 tiles, fused bias+relu+masked colsum ----
// 256 threads = 4 waves (2x2); wave tile 64x64 = 4x4 16x16 MFMA accs.
__global__ __launch_bounds__(256) void scorer_gemm_lds(
    const unsigned short* __restrict__ hb,    // [B,T,DIN] bf16
    const int*            __restrict__ text_len,
    const unsigned short* __restrict__ W1b,   // [DHID,DIN] bf16
    const float*          __restrict__ b1,
    float*                __restrict__ pooled) {

    const int tt  = blockIdx.x;
    const int b   = blockIdx.y;
    const int nt  = blockIdx.z;
    const int len = text_len[b];
    const int t0  = tt * BM;
    if (t0 >= len) return;                    // fully masked tile
    const int n0  = nt * BN;

    __shared__ unsigned short lds[(BM + BN) * BK];   // 32 KB
    unsigned short* As = lds;                 // [BM][BK]
    unsigned short* Bs = lds + BM * BK;       // [BN][BK]

    const int tid  = threadIdx.x;
    const int lane = tid & 63;
    const int wid  = tid >> 6;
    const int wr   = wid >> 1;                // wave m offset /64
    const int wc   = wid & 1;                 // wave n offset /64
    const int quad = lane >> 4;
    const int l15  = lane & 15;

    // staging: segment s covers LDS bytes [s*1024, s*1024+1023] = rows 8s..8s+7
    // lane l -> row 8s + (l>>3), k-col (l&7)*8 ; dest = base + lane*16 (implicit)
    const int srow = lane >> 3;
    const int skc  = (lane & 7) * 8;

    f32x4 acc[4][4] = {};
    const size_t abase = ((size_t)b * T_ + t0) * DIN;

    for (int kt = 0; kt < DIN / BK; ++kt) {
        const int k0 = kt * BK;
#pragma unroll
        for (int j = 0; j < 4; ++j) {
            int s = wid * 4 + j;
            int row = s * 8 + srow;
            const unsigned short* gp = hb + abase + (size_t)row * DIN + k0 + skc;
            __builtin_amdgcn_global_load_lds(
                (const __attribute__((address_space(1))) void*)gp,
                (__attribute__((address_space(3))) void*)(As + s * 512),
                16, 0, 0);
        }
#pragma unroll
        for (int j = 0; j < 4; ++j) {
            int s = wid * 4 + j;
            int row = s * 8 + srow;
            const unsigned short* gp = W1b + (size_t)(n0 + row) * DIN + k0 + skc;
            __builtin_amdgcn_global_load_lds(
                (const __attribute__((address_space(1))) void*)gp,
                (__attribute__((address_space(3))) void*)(Bs + s * 512),
                16, 0, 0);
        }
        __syncthreads();

#pragma unroll
        for (int kk = 0; kk < 2; ++kk) {
            BF8 a[4], w[4];
#pragma unroll
            for (int mi = 0; mi < 4; ++mi)
                a[mi].i = *(const i32x4*)(As + (wr * 64 + mi * 16 + l15) * BK + kk * 32 + quad * 8);
#pragma unroll
            for (int ni = 0; ni < 4; ++ni)
                w[ni].i = *(const i32x4*)(Bs + (wc * 64 + ni * 16 + l15) * BK + kk * 32 + quad * 8);
#pragma unroll
            for (int mi = 0; mi < 4; ++mi)
#pragma unroll
                for (int ni = 0; ni < 4; ++ni)
                    acc[mi][ni] = __builtin_amdgcn_mfma_f32_16x16x32_bf16(
                        a[mi].v, w[ni].v, acc[mi][ni], 0, 0, 0);
        }
        __syncthreads();
    }

    // epilogue: +b1, relu, mask, reduce over m (regs then quad-shfl), atomicAdd
    // C/D layout: col = lane&15 (n), row = quad*4 + reg (m)
#pragma unroll
    for (int ni = 0; ni < 4; ++ni) {
        int n = n0 + wc * 64 + ni * 16 + l15;
        float bias = b1[n];
        float colsum = 0.f;
#pragma unroll
        for (int mi = 0; mi < 4; ++mi) {
            int trow = t0 + wr * 64 + mi * 16 + quad * 4;
#pragma unroll
            for (int r = 0; r < 4; ++r) {
                float v = acc[mi][ni][r] + bias;
                v = v > 0.f ? v : 0.f;
                if (trow + r < len) colsum += v;
            }
        }
        colsum += __shfl_xor(colsum, 16);
        colsum += __shfl_xor(colsum, 32);
        if (quad == 0) atomicAdd(&pooled[b * DHID + n], colsum);
    }
}

// ---- fallback (round-2 structure) if ws too small for h-bf16 ----
__global__ void scorer_gemm_direct(const float* __restrict__ hin,
                                   const int*   __restrict__ text_len,
                                   const unsigned short* __restrict__ W1b,
                                   const float* __restrict__ b1,
                                   float*       __restrict__ pooled) {
    const int tt  = blockIdx.x;
    const int b   = blockIdx.y;
    const int len = text_len[b];
    const int t0  = tt * 64;
    if (t0 >= len) return;
    const int tid = threadIdx.x, lane = tid & 63, wid = tid >> 6;
    const int wrow = wid >> 1, wcol = wid & 1, quad = lane >> 4, l15 = lane & 15;
    const float* aptr[2];
#pragma unroll
    for (int mi = 0; mi < 2; ++mi)
        aptr[mi] = hin + ((size_t)b * T_ + t0 + wrow * 32 + mi * 16 + l15) * DIN + quad * 8;
    for (int nout = 0; nout < DHID / 128; ++nout) {
        const int nbase = nout * 128;
        f32x4 acc[2][4] = {};
        const unsigned short* bptr[4];
        float b1v[4];
#pragma unroll
        for (int ni = 0; ni < 4; ++ni) {
            int n = nbase + wcol * 64 + ni * 16 + l15;
            bptr[ni] = W1b + (size_t)n * DIN + quad * 8;
            b1v[ni]  = b1[n];
        }
        for (int k = 0; k < DIN; k += 32) {
            BF8 a[2], w[4];
#pragma unroll
            for (int mi = 0; mi < 2; ++mi) {
                float4 f0 = *(const float4*)(aptr[mi] + k);
                float4 f1 = *(const float4*)(aptr[mi] + k + 4);
                a[mi].u[0] = pack2bf(f0.x, f0.y);
                a[mi].u[1] = pack2bf(f0.z, f0.w);
                a[mi].u[2] = pack2bf(f1.x, f1.y);
                a[mi].u[3] = pack2bf(f1.z, f1.w);
            }
#pragma unroll
            for (int ni = 0; ni < 4; ++ni) w[ni].i = *(const i32x4*)(bptr[ni] + k);
#pragma unroll
            for (int mi = 0; mi < 2; ++mi)
#pragma unroll
                for (int ni = 0; ni < 4; ++ni)
                    acc[mi][ni] = __builtin_amdgcn_mfma_f32_16x16x32_bf16(
                        a[mi].v, w[ni].v, acc[mi][ni], 0, 0, 0);
        }
#pragma unroll
        for (int ni = 0; ni < 4; ++ni) {
            float colsum = 0.f;
#pragma unroll
            for (int mi = 0; mi < 2; ++mi) {
                int trow = t0 + wrow * 32 + mi * 16 + quad * 4;
#pragma unroll
                for (int r = 0; r < 4; ++r) {
                    float v = acc[mi][ni][r] + b1v[ni];
                    v = v > 0.f ? v : 0.f;
                    if (trow + r < len) colsum += v;
                }
            }
            colsum += __shfl_xor(colsum, 16);
            colsum += __shfl_xor(colsum, 32);
            if (quad == 0)
                atomicAdd(&pooled[b * DHID + nbase + wcol * 64 + ni * 16 + l15], colsum);
        }
    }
}

// ---- score[b][tag] = pooled[b]·W2[tag] / len + b2[tag] ----
__global__ void finalize_k(const float* __restrict__ pooled,
                           const int*   __restrict__ text_len,
                           const float* __restrict__ W2,
                           const float* __restrict__ b2,
                           float*       __restrict__ out) {
    int b = blockIdx.x, tid = threadIdx.x;
    float s0 = 0.f, s1 = 0.f;
    for (int hh = tid; hh < DHID; hh += 256) {
        float p = pooled[b * DHID + hh];
        s0 += p * W2[hh];
        s1 += p * W2[DHID + hh];
    }
#pragma unroll
    for (int off = 32; off > 0; off >>= 1) {
        s0 += __shfl_down(s0, off);
        s1 += __shfl_down(s1, off);
    }
    __shared__ float r0[4], r1[4];
    int wid = tid >> 6, lane = tid & 63;
    if (lane == 0) { r0[wid] = s0; r1[wid] = s1; }
    __syncthreads();
    if (tid == 0) {
        float inv = 1.0f / (float)text_len[b];
        out[b * 2 + 0] = (r0[0] + r0[1] + r0[2] + r0[3]) * inv + b2[0];
        out[b * 2 + 1] = (r1[0] + r1[1] + r1[2] + r1[3]) * inv + b2[1];
    }
}

extern "C" void kernel_launch(void* const* d_in, const int* in_sizes, int n_in,
                              void* d_out, int out_size, void* d_ws, size_t ws_size,
                              hipStream_t stream) {
    const float* hin      = (const float*)d_in[0];
    const int*   text_len = (const int*)  d_in[1];
    const float* W1       = (const float*)d_in[2];
    const float* b1       = (const float*)d_in[3];
    const float* W2       = (const float*)d_in[4];
    const float* b2       = (const float*)d_in[5];
    float* out = (float*)d_out;

    const size_t HB_BYTES  = (size_t)B_ * T_ * DIN * 2;        // 134 MB
    const size_t W1B_BYTES = (size_t)DHID * DIN * 2;           // 4 MB
    const size_t NEED      = HB_BYTES + W1B_BYTES + (size_t)B_ * DHID * 4;

    if (ws_size >= NEED) {
        unsigned short* hb     = (unsigned short*)d_ws;
        unsigned short* W1b    = (unsigned short*)((char*)d_ws + HB_BYTES);
        float*          pooled = (float*)((char*)d_ws + HB_BYTES + W1B_BYTES);

        (void)hipMemsetAsync(pooled, 0, B_ * DHID * sizeof(float), stream);
        convert_w1<<<(DHID * DIN / 4) / 256, 256, 0, stream>>>(W1, W1b);
        convert_h<<<((size_t)B_ * T_ * DIN / 8) / 256, 256, 0, stream>>>(hin, text_len, hb);

        dim3 grid(T_ / BM, B_, DHID / BN);
        scorer_gemm_lds<<<grid, 256, 0, stream>>>(hb, text_len, W1b, b1, pooled);
        finalize_k<<<B_, 256, 0, stream>>>(pooled, text_len, W2, b2, out);
    } else {
        unsigned short* W1b    = (unsigned short*)d_ws;
        float*          pooled = (float*)((char*)d_ws + W1B_BYTES);
        (void)hipMemsetAsync(pooled, 0, B_ * DHID * sizeof(float), stream);
        convert_w1<<<(DHID * DIN / 4) / 256, 256, 0, stream>>>(W1, W1b);
        dim3 grid(T_ / 64, B_);
        scorer_gemm_direct<<<grid, 256, 0, stream>>>(hin, text_len, W1b, b1, pooled);
        finalize_k<<<B_, 256, 0, stream>>>(pooled, text_len, W2, b2, out);
    }
}

// Round 4
// 567.092 us; speedup vs baseline: 3.6789x; 1.3591x over previous
//
#include <hip/hip_runtime.h>
#include <hip/hip_bf16.h>

#define B_   32
#define T_   2048
#define DIN  1024
#define DHID 2048
#define BM   128
#define BN   128
#define BK   64

typedef __attribute__((ext_vector_type(8))) short bf16x8;   // 8 bf16 = 4 VGPRs
typedef __attribute__((ext_vector_type(4))) float f32x4;
typedef __attribute__((ext_vector_type(4))) int   i32x4;

union BF8 { bf16x8 v; i32x4 i; unsigned int u[4]; };

// fp32 -> bf16 round-to-nearest-even, pure integer ops
__device__ inline unsigned int f2bf_u(float f) {
    unsigned int u = __float_as_uint(f);
    return (u + 0x7FFFu + ((u >> 16) & 1u)) >> 16;
}
__device__ inline unsigned int pack2bf(float a, float b) {
    return f2bf_u(a) | (f2bf_u(b) << 16);
}

// ---- W1 fp32 [DHID][DIN] -> bf16 same layout; also zero pooled ----
__global__ void convert_w1(const float* __restrict__ W1,
                           unsigned short* __restrict__ W1b,
                           float* __restrict__ pooled) {
    int idx = blockIdx.x * blockDim.x + threadIdx.x;   // one float4 per thread
    float4 f = ((const float4*)W1)[idx];
    ((uint2*)W1b)[idx] = uint2{pack2bf(f.x, f.y), pack2bf(f.z, f.w)};
    if (idx < B_ * DHID / 4) ((float4*)pooled)[idx] = float4{0.f, 0.f, 0.f, 0.f};
}

// ---- h fp32 [B,T,DIN] -> bf16; masked rows (t >= len) -> zeros ----
// grid: (T_*DIN/8/256, B_); shift-only indexing (DIN=1024, 8 elem/thread)
__global__ void convert_h(const float* __restrict__ h,
                          const int*   __restrict__ text_len,
                          unsigned short* __restrict__ hb) {
    const int b   = blockIdx.y;
    const int idx = blockIdx.x * 256 + threadIdx.x;       // 0 .. T_*DIN/8-1
    const int t   = idx >> 7;                             // DIN/8 = 128 thr/row
    const size_t gi = (size_t)b * (T_ * DIN / 8) + idx;   // uint4 index
    uint4 o;
    if (t < text_len[b]) {
        float4 f0 = ((const float4*)h)[gi * 2];
        float4 f1 = ((const float4*)h)[gi * 2 + 1];
        o.x = pack2bf(f0.x, f0.y);
        o.y = pack2bf(f0.z, f0.w);
        o.z = pack2bf(f1.x, f1.y);
        o.w = pack2bf(f1.z, f1.w);
    } else {
        o = uint4{0u, 0u, 0u, 0u};
    }
    ((uint4*)hb)[gi] = o;
}

// ---- main GEMM: LDS-staged 128x128x64, XOR-swizzled LDS, fused epilogue ----
// 256 threads = 4 waves (2x2); wave tile 64x64 = 4x4 16x16x32 MFMA accs.
// LDS layout: 16B chunk c of row r stored at slot (c ^ (r&7)) within row.
__global__ __launch_bounds__(256) void scorer_gemm_lds(
    const unsigned short* __restrict__ hb,    // [B,T,DIN] bf16
    const int*            __restrict__ text_len,
    const unsigned short* __restrict__ W1b,   // [DHID,DIN] bf16
    const float*          __restrict__ b1,
    float*                __restrict__ pooled) {

    const int nt  = blockIdx.x;               // n fastest -> A-tile L2 reuse
    const int tt  = blockIdx.y;
    const int b   = blockIdx.z;
    const int len = text_len[b];
    const int t0  = tt * BM;
    if (t0 >= len) return;                    // fully masked tile
    const int n0  = nt * BN;

    __shared__ unsigned short lds[(BM + BN) * BK];   // 32 KB
    unsigned short* As = lds;                 // swizzled [BM][BK]
    unsigned short* Bs = lds + BM * BK;       // swizzled [BN][BK]

    const int tid  = threadIdx.x;
    const int lane = tid & 63;
    const int wid  = tid >> 6;
    const int wr   = wid >> 1;                // wave m offset /64
    const int wc   = wid & 1;                 // wave n offset /64
    const int quad = lane >> 4;
    const int l15  = lane & 15;
    const int sw   = l15 & 7;                 // row&7 for fragment reads

    // staging: segment s = 1024B = rows 8s..8s+7; lane l -> LDS s*1024+l*16.
    // row r = 8s + (l>>3); slot = l&7 holds chunk c = slot ^ (r&7).
    const int srow = lane >> 3;
    const int schunk = (lane & 7) ^ ((lane >> 3) & 7);
    const int skc  = schunk * 8;              // k-offset in elements

    f32x4 acc[4][4] = {};
    const size_t abase = ((size_t)b * T_ + t0) * DIN;

    for (int kt = 0; kt < DIN / BK; ++kt) {
        const int k0 = kt * BK;
#pragma unroll
        for (int j = 0; j < 4; ++j) {
            int s = wid * 4 + j;
            int row = s * 8 + srow;
            const unsigned short* gp = hb + abase + (size_t)row * DIN + k0 + skc;
            __builtin_amdgcn_global_load_lds(
                (const __attribute__((address_space(1))) void*)gp,
                (__attribute__((address_space(3))) void*)(As + s * 512),
                16, 0, 0);
        }
#pragma unroll
        for (int j = 0; j < 4; ++j) {
            int s = wid * 4 + j;
            int row = s * 8 + srow;
            const unsigned short* gp = W1b + (size_t)(n0 + row) * DIN + k0 + skc;
            __builtin_amdgcn_global_load_lds(
                (const __attribute__((address_space(1))) void*)gp,
                (__attribute__((address_space(3))) void*)(Bs + s * 512),
                16, 0, 0);
        }
        __syncthreads();

#pragma unroll
        for (int kk = 0; kk < 2; ++kk) {
            BF8 a[4], w[4];
            const int chunk = (kk * 4 + quad) ^ sw;     // swizzled k-chunk slot
#pragma unroll
            for (int mi = 0; mi < 4; ++mi)
                a[mi].i = *(const i32x4*)(As + (wr * 64 + mi * 16 + l15) * BK + chunk * 8);
#pragma unroll
            for (int ni = 0; ni < 4; ++ni)
                w[ni].i = *(const i32x4*)(Bs + (wc * 64 + ni * 16 + l15) * BK + chunk * 8);
#pragma unroll
            for (int mi = 0; mi < 4; ++mi)
#pragma unroll
                for (int ni = 0; ni < 4; ++ni)
                    acc[mi][ni] = __builtin_amdgcn_mfma_f32_16x16x32_bf16(
                        a[mi].v, w[ni].v, acc[mi][ni], 0, 0, 0);
        }
        __syncthreads();
    }

    // epilogue: +b1, relu, mask, reduce over m (regs then quad-shfl), atomicAdd
    // C/D layout: col = lane&15 (n), row = quad*4 + reg (m)
#pragma unroll
    for (int ni = 0; ni < 4; ++ni) {
        int n = n0 + wc * 64 + ni * 16 + l15;
        float bias = b1[n];
        float colsum = 0.f;
#pragma unroll
        for (int mi = 0; mi < 4; ++mi) {
            int trow = t0 + wr * 64 + mi * 16 + quad * 4;
#pragma unroll
            for (int r = 0; r < 4; ++r) {
                float v = acc[mi][ni][r] + bias;
                v = v > 0.f ? v : 0.f;
                if (trow + r < len) colsum += v;
            }
        }
        colsum += __shfl_xor(colsum, 16);
        colsum += __shfl_xor(colsum, 32);
        if (quad == 0) atomicAdd(&pooled[b * DHID + n], colsum);
    }
}

// ---- fallback (round-2 structure) if ws too small for h-bf16 ----
__global__ void scorer_gemm_direct(const float* __restrict__ hin,
                                   const int*   __restrict__ text_len,
                                   const unsigned short* __restrict__ W1b,
                                   const float* __restrict__ b1,
                                   float*       __restrict__ pooled) {
    const int tt  = blockIdx.x;
    const int b   = blockIdx.y;
    const int len = text_len[b];
    const int t0  = tt * 64;
    if (t0 >= len) return;
    const int tid = threadIdx.x, lane = tid & 63, wid = tid >> 6;
    const int wrow = wid >> 1, wcol = wid & 1, quad = lane >> 4, l15 = lane & 15;
    const float* aptr[2];
#pragma unroll
    for (int mi = 0; mi < 2; ++mi)
        aptr[mi] = hin + ((size_t)b * T_ + t0 + wrow * 32 + mi * 16 + l15) * DIN + quad * 8;
    for (int nout = 0; nout < DHID / 128; ++nout) {
        const int nbase = nout * 128;
        f32x4 acc[2][4] = {};
        const unsigned short* bptr[4];
        float b1v[4];
#pragma unroll
        for (int ni = 0; ni < 4; ++ni) {
            int n = nbase + wcol * 64 + ni * 16 + l15;
            bptr[ni] = W1b + (size_t)n * DIN + quad * 8;
            b1v[ni]  = b1[n];
        }
        for (int k = 0; k < DIN; k += 32) {
            BF8 a[2], w[4];
#pragma unroll
            for (int mi = 0; mi < 2; ++mi) {
                float4 f0 = *(const float4*)(aptr[mi] + k);
                float4 f1 = *(const float4*)(aptr[mi] + k + 4);
                a[mi].u[0] = pack2bf(f0.x, f0.y);
                a[mi].u[1] = pack2bf(f0.z, f0.w);
                a[mi].u[2] = pack2bf(f1.x, f1.y);
                a[mi].u[3] = pack2bf(f1.z, f1.w);
            }
#pragma unroll
            for (int ni = 0; ni < 4; ++ni) w[ni].i = *(const i32x4*)(bptr[ni] + k);
#pragma unroll
            for (int mi = 0; mi < 2; ++mi)
#pragma unroll
                for (int ni = 0; ni < 4; ++ni)
                    acc[mi][ni] = __builtin_amdgcn_mfma_f32_16x16x32_bf16(
                        a[mi].v, w[ni].v, acc[mi][ni], 0, 0, 0);
        }
#pragma unroll
        for (int ni = 0; ni < 4; ++ni) {
            float colsum = 0.f;
#pragma unroll
            for (int mi = 0; mi < 2; ++mi) {
                int trow = t0 + wrow * 32 + mi * 16 + quad * 4;
#pragma unroll
                for (int r = 0; r < 4; ++r) {
                    float v = acc[mi][ni][r] + b1v[ni];
                    v = v > 0.f ? v : 0.f;
                    if (trow + r < len) colsum += v;
                }
            }
            colsum += __shfl_xor(colsum, 16);
            colsum += __shfl_xor(colsum, 32);
            if (quad == 0)
                atomicAdd(&pooled[b * DHID + nbase + wcol * 64 + ni * 16 + l15], colsum);
        }
    }
}

// ---- score[b][tag] = pooled[b]·W2[tag] / len + b2[tag] ----
__global__ void finalize_k(const float* __restrict__ pooled,
                           const int*   __restrict__ text_len,
                           const float* __restrict__ W2,
                           const float* __restrict__ b2,
                           float*       __restrict__ out) {
    int b = blockIdx.x, tid = threadIdx.x;
    float s0 = 0.f, s1 = 0.f;
    for (int hh = tid; hh < DHID; hh += 256) {
        float p = pooled[b * DHID + hh];
        s0 += p * W2[hh];
        s1 += p * W2[DHID + hh];
    }
#pragma unroll
    for (int off = 32; off > 0; off >>= 1) {
        s0 += __shfl_down(s0, off);
        s1 += __shfl_down(s1, off);
    }
    __shared__ float r0[4], r1[4];
    int wid = tid >> 6, lane = tid & 63;
    if (lane == 0) { r0[wid] = s0; r1[wid] = s1; }
    __syncthreads();
    if (tid == 0) {
        float inv = 1.0f / (float)text_len[b];
        out[b * 2 + 0] = (r0[0] + r0[1] + r0[2] + r0[3]) * inv + b2[0];
        out[b * 2 + 1] = (r1[0] + r1[1] + r1[2] + r1[3]) * inv + b2[1];
    }
}

extern "C" void kernel_launch(void* const* d_in, const int* in_sizes, int n_in,
                              void* d_out, int out_size, void* d_ws, size_t ws_size,
                              hipStream_t stream) {
    const float* hin      = (const float*)d_in[0];
    const int*   text_len = (const int*)  d_in[1];
    const float* W1       = (const float*)d_in[2];
    const float* b1       = (const float*)d_in[3];
    const float* W2       = (const float*)d_in[4];
    const float* b2       = (const float*)d_in[5];
    float* out = (float*)d_out;

    const size_t HB_BYTES  = (size_t)B_ * T_ * DIN * 2;        // 134 MB
    const size_t W1B_BYTES = (size_t)DHID * DIN * 2;           // 4 MB
    const size_t NEED      = HB_BYTES + W1B_BYTES + (size_t)B_ * DHID * 4;

    if (ws_size >= NEED) {
        unsigned short* hb     = (unsigned short*)d_ws;
        unsigned short* W1b    = (unsigned short*)((char*)d_ws + HB_BYTES);
        float*          pooled = (float*)((char*)d_ws + HB_BYTES + W1B_BYTES);

        convert_w1<<<(DHID * DIN / 4) / 256, 256, 0, stream>>>(W1, W1b, pooled);
        dim3 hgrid((T_ * DIN / 8) / 256, B_);
        convert_h<<<hgrid, 256, 0, stream>>>(hin, text_len, hb);

        dim3 grid(DHID / BN, T_ / BM, B_);
        scorer_gemm_lds<<<grid, 256, 0, stream>>>(hb, text_len, W1b, b1, pooled);
        finalize_k<<<B_, 256, 0, stream>>>(pooled, text_len, W2, b2, out);
    } else {
        unsigned short* W1b    = (unsigned short*)d_ws;
        float*          pooled = (float*)((char*)d_ws + W1B_BYTES);
        (void)hipMemsetAsync(pooled, 0, B_ * DHID * sizeof(float), stream);
        convert_w1<<<(DHID * DIN / 4) / 256, 256, 0, stream>>>(W1, W1b, pooled);
        dim3 grid(T_ / 64, B_);
        scorer_gemm_direct<<<grid, 256, 0, stream>>>(hin, text_len, W1b, b1, pooled);
        finalize_k<<<B_, 256, 0, stream>>>(pooled, text_len, W2, b2, out);
    }
}